// Round 2
// baseline (2426.059 us; speedup 1.0000x reference)
//
#include <hip/hip_runtime.h>

#define T_SEQ 1024
#define NBATCH 256
#define DIN 128
#define HID 64
#define DOUT 128

// ---------------- LDS layouts ----------------
// Encoder (per ping-pong buffer of 352 floats):
//  op0 [0..204):  [x:128 | h0:64], 4 k-slices of 48 at float-offsets 0,52,104,156
//                 x[k] -> k + 4*(k/48);  h0[j] -> 136+j (j<16) else 140+j
//  op1 [208..348): [h0:64 | h1:64]; slices of 32 padded to 36:
//                 h0[j] -> 208 + j + 4*(j>>5);  h1[j] -> 280 + j + 4*(j>>5)
// Decoder (overlaid on same buffers):
//  op0 [0..140):   [h1:64 | h0:64], pos(i) = i + 4*(i>>5); slices 0,36,72,108
//  op1 [144..284): [h0new:64 | h1old:64], pos = 144 + i + 4*(i>>5)
#define EOP1 208
#define DOP1 144
#define BUFSZ 352

#define TWO_LOG2E 2.8853900817779268f   // 2*log2(e)

typedef float v2f __attribute__((ext_vector_type(2)));

__device__ __forceinline__ float rcp_f(float x) { return __builtin_amdgcn_rcpf(x); }

__device__ __forceinline__ float exp2_f(float x) {
#if __has_builtin(__builtin_amdgcn_exp2f)
  return __builtin_amdgcn_exp2f(x);
#else
  return exp2f(x);
#endif
}

// tanh(x) with pre-scaled argument y = x*TWO_LOG2E:  tanh = 1 - 2/(1+2^y); inf-safe
__device__ __forceinline__ float tanh_pre(float y) {
  float m = exp2_f(y);
  return fmaf(-2.0f, rcp_f(1.0f + m), 1.0f);
}
__device__ __forceinline__ float tanh_full(float x) { return tanh_pre(x * TWO_LOG2E); }

// ds_swizzle BitMode (32-lane groups): src = ((lane & and) | or) ^ xor
template<int IMM>
__device__ __forceinline__ float swz(float v) {
  return __uint_as_float((unsigned)__builtin_amdgcn_ds_swizzle((int)__float_as_uint(v), IMM));
}

// quad-perm DPP butterfly add (lane^1: 0xB1, lane^2: 0x4E) on the VALU pipe
template<int CTRL>
__device__ __forceinline__ float dpp_add(float v) {
  int p = __builtin_amdgcn_update_dpp(0, __float_as_int(v), CTRL, 0xF, 0xF, true);
  return v + __int_as_float(p);
}

// LDS-only barrier: do NOT drain vmcnt (x prefetch loads / out stores stay in flight).
__device__ __forceinline__ void bar_lds() {
  asm volatile("s_waitcnt lgkmcnt(0)\n\ts_barrier" ::: "memory");
}

template<int N4>
__device__ __forceinline__ void loadrow(float* w, const float* p) {
#pragma unroll
  for (int k = 0; k < N4; ++k) {
    float4 q = ((const float4*)p)[k];
    w[4*k+0] = q.x; w[4*k+1] = q.y; w[4*k+2] = q.z; w[4*k+3] = q.w;
  }
}

// Packed-fp32 dot: K4 float4 iterations = 2*K4 v_pk_fma_f32.
// Two packed accumulator pairs = 4 independent fp32 chains (same ILP as before).
template<int K4>
__device__ __forceinline__ float dotp(const float* wf, const float4* v) {
  const v2f* w = (const v2f*)wf;
  v2f a0 = {0.f, 0.f}, a1 = {0.f, 0.f};
#pragma unroll
  for (int k = 0; k < K4; ++k) {
    float4 q = v[k];
    v2f q0 = {q.x, q.y};
    v2f q1 = {q.z, q.w};
    a0 = __builtin_elementwise_fma(w[2*k+0], q0, a0);
    a1 = __builtin_elementwise_fma(w[2*k+1], q1, a1);
  }
  v2f s = a0 + a1;   // v_pk_add_f32
  return s.x + s.y;
}

// Lane map: q = tid&3 (k-quarter), g = (tid>>2)&3 (gate i,f,g,o), j = tid>>4 (unit).
__device__ __forceinline__ float cell_update(float pre, float gsc, float gscl, float gof, float& c) {
  float a  = fmaf(gsc, tanh_pre(pre * gscl), gof);  // sigmoid for i,f,o ; tanh for g
  float i_s = swz<0x0010>(a);
  float f_s = swz<0x0090>(a);
  float g_t = swz<0x0110>(a);
  float o_s = swz<0x0190>(a);
  c = fmaf(f_s, c, i_s * g_t);
  return o_s * tanh_full(c);
}

// ---------------- prep kernel: C0 = dWih0 @ fcW  [256x64], fcbt = dWih0 @ fcb ----------------
__global__ void prep_kernel(const float* __restrict__ dWih0,
                            const float* __restrict__ fcW,
                            const float* __restrict__ fcb,
                            float* __restrict__ ws) {
  const int r = (int)blockIdx.x;           // 256 blocks
  const int jj = (int)threadIdx.x;         // 64 threads
  const float* wr = dWih0 + (size_t)r * DIN;
  float acc = 0.f;
  for (int o = 0; o < DIN; ++o) acc = fmaf(wr[o], fcW[(size_t)o * HID + jj], acc);
  ws[(size_t)r * HID + jj] = acc;
  if (jj == 0) {
    float a = 0.f;
    for (int o = 0; o < DIN; ++o) a = fmaf(wr[o], fcb[o], a);
    ws[256 * HID + r] = a;
  }
}

// ---------------- main persistent kernel: 1 block / batch element, 1024 threads ----------------
__global__ __launch_bounds__(1024, 4) void lstm_ae_kernel(
    const float* __restrict__ x,
    const float* __restrict__ eW0, const float* __restrict__ eU0,
    const float* __restrict__ ebi0, const float* __restrict__ ebh0,
    const float* __restrict__ eW1, const float* __restrict__ eU1,
    const float* __restrict__ ebi1, const float* __restrict__ ebh1,
    const float* __restrict__ dW0, const float* __restrict__ dU0,
    const float* __restrict__ dbi0, const float* __restrict__ dbh0,
    const float* __restrict__ dW1, const float* __restrict__ dU1,
    const float* __restrict__ dbi1, const float* __restrict__ dbh1,
    const float* __restrict__ fcW, const float* __restrict__ fcb,
    const float* __restrict__ ws,
    float* __restrict__ out)
{
  __shared__ __align__(16) float Abuf[BUFSZ];
  __shared__ __align__(16) float Bbuf[BUFSZ];

  const int tid = (int)threadIdx.x;
  const int b   = (int)blockIdx.x;
  const int q   = tid & 3;
  const int g   = (tid >> 2) & 3;
  const int j   = tid >> 4;
  const int r   = g * HID + j;

  const float gsc  = (g == 2) ? 1.0f : 0.5f;
  const float gof  = (g == 2) ? 0.0f : 0.5f;
  const float gscl = gsc * TWO_LOG2E;

  float w0[48];
  float w1[32];

  // ---------------- encoder weights ----------------
  if (q == 0)      loadrow<12>(w0, eW0 + (size_t)r * DIN);
  else if (q == 1) loadrow<12>(w0, eW0 + (size_t)r * DIN + 48);
  else if (q == 2) { loadrow<8>(w0, eW0 + (size_t)r * DIN + 96);
                     loadrow<4>(w0 + 32, eU0 + (size_t)r * HID); }
  else             loadrow<12>(w0, eU0 + (size_t)r * HID + 16);
  if (q < 2) loadrow<8>(w1, eW1 + (size_t)r * HID + 32 * q);
  else       loadrow<8>(w1, eU1 + (size_t)r * HID + 32 * (q - 2));
  float bs0 = ebi0[r] + ebh0[r];
  float bs1 = ebi1[r] + ebh1[r];

  const float* xb = x + (size_t)b * (T_SEQ * DIN);

  if (tid >= 136 && tid < BUFSZ) { Abuf[tid] = 0.f; Bbuf[tid] = 0.f; }   // h-slots = 0 (both bufs)
  if (tid < 32) {
    float4 v = ((const float4*)xb)[tid];
    ((float4*)Abuf)[tid + tid / 12] = v;                       // x_0 (padded)
  }
  float c0 = 0.f, c1 = 0.f;
  __syncthreads();

  // ---------------- phase 1: layer-skewed fused encoder (ONE barrier per step) ----------------
  // Phase t computes h0(t)   from [x(t)      | h0(t-1)]  (op0 region of R)
  //            and   h1(t-1) from [h0(t-1)   | h1(t-2)]  (op1 region of R)
  auto enc_phase = [&](float* R, float* W, int t) {
    float4 xn;
    const bool pf = (tid < 32) && (t + 1 < T_SEQ);
    if (pf) xn = ((const float4*)(xb + (size_t)(t + 1) * DIN))[tid];

    float p0 = dotp<12>(w0, (const float4*)R + 13 * q);
    float p1 = dotp<8>(w1, (const float4*)R + 52 + 9 * q);
    p0 = dpp_add<0xB1>(p0);
    p1 = dpp_add<0xB1>(p1);
    p0 = dpp_add<0x4E>(p0);
    p1 = dpp_add<0x4E>(p1);
    p0 += bs0;
    p1 += bs1;
    float h0v = cell_update(p0, gsc, gscl, gof, c0);
    float c1n = c1;
    float h1v = cell_update(p1, gsc, gscl, gof, c1n);
    if ((tid & 15) < 2)
      W[(tid & 15) ? (EOP1 + j + 4 * (j >> 5)) : ((j < 16) ? 136 + j : 140 + j)] = h0v;
    if (t > 0) {                               // t=0: h1(-1)/c1 stay at zero init
      c1 = c1n;
      if ((tid & 15) == 0) W[280 + j + 4 * (j >> 5)] = h1v;
    }
    if (pf) ((float4*)W)[tid + tid / 12] = xn; // stage x_{t+1}
    bar_lds();
  };

#pragma unroll 1
  for (int t = 0; t < T_SEQ; t += 2) {
    enc_phase(Abuf, Bbuf, t);
    enc_phase(Bbuf, Abuf, t + 1);
  }
  // epilogue phase: h1(T-1) from [h0(T-1) | h1(T-2)], final state lives in Abuf
  {
    float p1 = dotp<8>(w1, (const float4*)Abuf + 52 + 9 * q);
    p1 = dpp_add<0xB1>(p1);
    p1 = dpp_add<0x4E>(p1);
    p1 += bs1;
    float h1v = cell_update(p1, gsc, gscl, gof, c1);
    bar_lds();                                 // all reads of old h1 slot done before overwrite
    if ((tid & 15) == 0) Abuf[280 + j + 4 * (j >> 5)] = h1v;
  }
  float* R = Abuf;
  float* W = Bbuf;
  __syncthreads();

  // ---------------- transition: decoder weights + re-layout states ----------------
  const float* C0   = ws;
  const float* fcbt_arr = ws + 256 * HID;
  if (q < 2) loadrow<8>(w0, C0  + (size_t)r * HID + 32 * q);
  else       loadrow<8>(w0, dU0 + (size_t)r * HID + 32 * (q - 2));
  if (q < 2) loadrow<8>(w1, dW1 + (size_t)r * HID + 32 * q);
  else       loadrow<8>(w1, dU1 + (size_t)r * HID + 32 * (q - 2));
  float bs0d = dbi0[r] + dbh0[r];
  float bs1d = dbi1[r] + dbh1[r];
  float fcbt = fcbt_arr[r];

  const int e  = tid & 7;      // fc k-slice (8 floats)
  const int oo = tid >> 3;     // fc output index [0,128)
  float fw[8];
  loadrow<2>(fw, fcW + (size_t)oo * HID + 8 * e);
  float fb = fcb[oo];

  c0 = tanh_full(c0);
  c1 = tanh_full(c1);
  float hv = 0.f;
  if (tid < 64)        hv = tanh_full(R[(tid < 16) ? 136 + tid : 140 + tid]);        // h0enc
  else if (tid < 128)  { int jj = tid - 64; hv = tanh_full(R[280 + jj + 4*(jj>>5)]); } // h1enc
  __syncthreads();
  if (tid < 64)        R[72 + tid + 4 * (tid >> 5)] = hv;        // op0 h0 slot
  else if (tid < 128)  { int jj = tid - 64; R[216 + jj + 4*(jj>>5)] = hv; } // op1 h1old
  else if (tid < 196)  R[tid - 128] = 0.f;                       // op0 h1 slot = 0 (t=0: pred_{-1}=0)
  __syncthreads();

  float* outb = out + (size_t)b * (T_SEQ * DOUT);

  // ---------------- phase 2: autoregressive decoder (fc folded via C0) ----------------
  auto dec_step = [&](float* R_, float* W_, int t) {
    // layer-0 dot on [h1_{t-1} | h0_{t-1}]  (K=128)
    float p0 = dotp<8>(w0, (const float4*)R_ + 9 * q);
    // fc for pred_{t-1} (output only; off the critical path), reads R_ h1 slot
    float s = dotp<2>(fw, (const float4*)R_ + 2 * e + (e >> 2));
    p0 = dpp_add<0xB1>(p0);
    p0 = dpp_add<0x4E>(p0);
    p0 += bs0d;
    if (t > 0) p0 += fcbt;                      // composite fcb term (absent at t=0)
    float h0v = cell_update(p0, gsc, gscl, gof, c0);
    if ((tid & 15) < 2)
      W_[(tid & 15) ? (72 + j + 4 * (j >> 5)) : (DOP1 + j + 4 * (j >> 5))] = h0v;
    s = dpp_add<0xB1>(s);
    s = dpp_add<0x4E>(s);
    s += swz<0x101F>(s);                        // xor 4
    if (e == 0 && t > 0) outb[(size_t)(t - 1) * DOUT + oo] = s + fb;
    bar_lds();

    const float* bb = (q < 2) ? W_ : R_;        // [h0new | h1old]
    float p1 = dotp<8>(w1, (const float4*)bb + 36 + 9 * q);
    p1 = dpp_add<0xB1>(p1);
    p1 = dpp_add<0x4E>(p1);
    p1 += bs1d;
    float h1v = cell_update(p1, gsc, gscl, gof, c1);
    if ((tid & 15) < 2)
      W_[(tid & 15) ? (j + 4 * (j >> 5)) : (216 + j + 4 * (j >> 5))] = h1v;
    bar_lds();
  };

#pragma unroll 1
  for (int t = 0; t < T_SEQ; t += 2) {
    dec_step(R, W, t);
    dec_step(W, R, t + 1);
  }

  // epilogue: pred_{1023} from final h1 (in R)
  float s = dotp<2>(fw, (const float4*)R + 2 * e + (e >> 2));
  s = dpp_add<0xB1>(s);
  s = dpp_add<0x4E>(s);
  s += swz<0x101F>(s);
  if (e == 0) outb[(size_t)(T_SEQ - 1) * DOUT + oo] = s + fb;
}

extern "C" void kernel_launch(void* const* d_in, const int* in_sizes, int n_in,
                              void* d_out, int out_size, void* d_ws, size_t ws_size,
                              hipStream_t stream) {
  (void)in_sizes; (void)n_in; (void)ws_size; (void)out_size;
  const float* x    = (const float*)d_in[0];
  const float* eW0  = (const float*)d_in[1];
  const float* eU0  = (const float*)d_in[2];
  const float* ebi0 = (const float*)d_in[3];
  const float* ebh0 = (const float*)d_in[4];
  const float* eW1  = (const float*)d_in[5];
  const float* eU1  = (const float*)d_in[6];
  const float* ebi1 = (const float*)d_in[7];
  const float* ebh1 = (const float*)d_in[8];
  const float* dW0  = (const float*)d_in[9];
  const float* dU0  = (const float*)d_in[10];
  const float* dbi0 = (const float*)d_in[11];
  const float* dbh0 = (const float*)d_in[12];
  const float* dW1  = (const float*)d_in[13];
  const float* dU1  = (const float*)d_in[14];
  const float* dbi1 = (const float*)d_in[15];
  const float* dbh1 = (const float*)d_in[16];
  const float* fcW  = (const float*)d_in[17];
  const float* fcb  = (const float*)d_in[18];
  float* ws  = (float*)d_ws;
  float* out = (float*)d_out;

  hipLaunchKernelGGL(prep_kernel, dim3(256), dim3(64), 0, stream, dW0, fcW, fcb, ws);
  hipLaunchKernelGGL(lstm_ae_kernel, dim3(NBATCH), dim3(1024), 0, stream,
                     x, eW0, eU0, ebi0, ebh0, eW1, eU1, ebi1, ebh1,
                     dW0, dU0, dbi0, dbh0, dW1, dU1, dbi1, dbh1,
                     fcW, fcb, ws, out);
}

// Round 3
// 2363.860 us; speedup vs baseline: 1.0263x; 1.0263x over previous
//
#include <hip/hip_runtime.h>

#define T_SEQ 1024
#define NBATCH 256
#define DIN 128
#define HID 64
#define DOUT 128

// ---------------- LDS layouts ----------------
// Encoder (per ping-pong buffer of 352 floats):
//  op0 [0..204):  [x:128 | h0:64], 4 k-slices of 48 at float-offsets 0,52,104,156
//                 x[k] -> k + 4*(k/48);  h0[j] -> 136+j (j<16) else 140+j
//  op1 [208..348): [h0:64 | h1:64]; slices of 32 padded to 36:
//                 h0[j] -> 208 + j + 4*(j>>5);  h1[j] -> 280 + j + 4*(j>>5)
// Decoder (overlaid on same buffers):
//  op0 [0..140):   [h1:64 | h0:64], pos(i) = i + 4*(i>>5); slices 0,36,72,108
//  op1 [144..284): [h0new:64 | h1old:64], pos = 144 + i + 4*(i>>5)
#define EOP1 208
#define DOP1 144
#define BUFSZ 352

#define TWO_LOG2E 2.8853900817779268f   // 2*log2(e)

typedef float v2f __attribute__((ext_vector_type(2)));

__device__ __forceinline__ float rcp_f(float x) { return __builtin_amdgcn_rcpf(x); }

__device__ __forceinline__ float exp2_f(float x) {
#if __has_builtin(__builtin_amdgcn_exp2f)
  return __builtin_amdgcn_exp2f(x);
#else
  return exp2f(x);
#endif
}

// tanh(x) with pre-scaled argument y = x*TWO_LOG2E:  tanh = 1 - 2/(1+2^y); inf-safe
__device__ __forceinline__ float tanh_pre(float y) {
  float m = exp2_f(y);
  return fmaf(-2.0f, rcp_f(1.0f + m), 1.0f);
}
__device__ __forceinline__ float tanh_full(float x) { return tanh_pre(x * TWO_LOG2E); }

// quad-perm DPP butterfly add (lane^1: 0xB1, lane^2: 0x4E) on the VALU pipe
template<int CTRL>
__device__ __forceinline__ float dpp_add(float v) {
  int p = __builtin_amdgcn_update_dpp(0, __float_as_int(v), CTRL, 0xF, 0xF, true);
  return v + __int_as_float(p);
}

// DPP mov: CTRL 0x100|N = row_shl:N  -> dst lane i gets src lane i+N (within 16-lane row;
// out-of-row lanes read 0 via bound_ctrl). VALU pipe - replaces ds_swizzle gate gathers.
template<int CTRL>
__device__ __forceinline__ float dpp_mov(float v) {
  int p = __builtin_amdgcn_update_dpp(0, __float_as_int(v), CTRL, 0xF, 0xF, true);
  return __int_as_float(p);
}

// LDS-only barrier: do NOT drain vmcnt (x prefetch loads / out stores stay in flight).
__device__ __forceinline__ void bar_lds() {
  asm volatile("s_waitcnt lgkmcnt(0)\n\ts_barrier" ::: "memory");
}

template<int N4>
__device__ __forceinline__ void loadrow(float* w, const float* p) {
#pragma unroll
  for (int k = 0; k < N4; ++k) {
    float4 q = ((const float4*)p)[k];
    w[4*k+0] = q.x; w[4*k+1] = q.y; w[4*k+2] = q.z; w[4*k+3] = q.w;
  }
}

// Packed-fp32 dot: K4 float4 iterations = 2*K4 v_pk_fma_f32.
template<int K4>
__device__ __forceinline__ float dotp(const float* wf, const float4* v) {
  const v2f* w = (const v2f*)wf;
  v2f a0 = {0.f, 0.f}, a1 = {0.f, 0.f};
#pragma unroll
  for (int k = 0; k < K4; ++k) {
    float4 q = v[k];
    v2f q0 = {q.x, q.y};
    v2f q1 = {q.z, q.w};
    a0 = __builtin_elementwise_fma(w[2*k+0], q0, a0);
    a1 = __builtin_elementwise_fma(w[2*k+1], q1, a1);
  }
  v2f s = a0 + a1;   // v_pk_add_f32
  return s.x + s.y;
}

// Lane map: q = tid&3 (k-quarter), g = (tid>>2)&3 (gate i,f,g,o), j = tid>>4 (unit).
// After the quad butterfly, `a` is quad-uniform: lanes 0-3 of each 16-lane unit group
// hold gate i, 4-7 f, 8-11 g~, 12-15 o. Gather f/g~/o into lanes 0-3 with row_shl DPP
// (VALU) instead of ds_swizzle (LDS pipe). c/h are VALID ONLY in lanes 0-3 of each
// group — exactly the lanes that carry c across steps and write h ((tid&15)<2).
__device__ __forceinline__ float cell_update(float pre, float gsc, float gscl, float gof, float& c) {
  float a  = fmaf(gsc, tanh_pre(pre * gscl), gof);  // sigmoid for i,f,o ; tanh for g
  float f_s = dpp_mov<0x104>(a);   // lane i <- i+4   (f)
  float g_t = dpp_mov<0x108>(a);   // lane i <- i+8   (g~)
  float o_s = dpp_mov<0x10C>(a);   // lane i <- i+12  (o)
  c = fmaf(f_s, c, a * g_t);       // a == i in lanes 0-3
  return o_s * tanh_full(c);
}

// ---------------- prep kernel: C0 = dWih0 @ fcW  [256x64], fcbt = dWih0 @ fcb ----------------
__global__ void prep_kernel(const float* __restrict__ dWih0,
                            const float* __restrict__ fcW,
                            const float* __restrict__ fcb,
                            float* __restrict__ ws) {
  const int r = (int)blockIdx.x;           // 256 blocks
  const int jj = (int)threadIdx.x;         // 64 threads
  const float* wr = dWih0 + (size_t)r * DIN;
  float acc = 0.f;
  for (int o = 0; o < DIN; ++o) acc = fmaf(wr[o], fcW[(size_t)o * HID + jj], acc);
  ws[(size_t)r * HID + jj] = acc;
  if (jj == 0) {
    float a = 0.f;
    for (int o = 0; o < DIN; ++o) a = fmaf(wr[o], fcb[o], a);
    ws[256 * HID + r] = a;
  }
}

// ---------------- main persistent kernel: 1 block / batch element, 1024 threads ----------------
__global__ __launch_bounds__(1024, 4) void lstm_ae_kernel(
    const float* __restrict__ x,
    const float* __restrict__ eW0, const float* __restrict__ eU0,
    const float* __restrict__ ebi0, const float* __restrict__ ebh0,
    const float* __restrict__ eW1, const float* __restrict__ eU1,
    const float* __restrict__ ebi1, const float* __restrict__ ebh1,
    const float* __restrict__ dW0, const float* __restrict__ dU0,
    const float* __restrict__ dbi0, const float* __restrict__ dbh0,
    const float* __restrict__ dW1, const float* __restrict__ dU1,
    const float* __restrict__ dbi1, const float* __restrict__ dbh1,
    const float* __restrict__ fcW, const float* __restrict__ fcb,
    const float* __restrict__ ws,
    float* __restrict__ out)
{
  __shared__ __align__(16) float Abuf[BUFSZ];
  __shared__ __align__(16) float Bbuf[BUFSZ];

  const int tid = (int)threadIdx.x;
  const int b   = (int)blockIdx.x;
  const int q   = tid & 3;
  const int g   = (tid >> 2) & 3;
  const int j   = tid >> 4;
  const int r   = g * HID + j;

  const float gsc  = (g == 2) ? 1.0f : 0.5f;
  const float gof  = (g == 2) ? 0.0f : 0.5f;
  const float gscl = gsc * TWO_LOG2E;

  float w0[48];
  float w1[32];

  // ---------------- encoder weights ----------------
  if (q == 0)      loadrow<12>(w0, eW0 + (size_t)r * DIN);
  else if (q == 1) loadrow<12>(w0, eW0 + (size_t)r * DIN + 48);
  else if (q == 2) { loadrow<8>(w0, eW0 + (size_t)r * DIN + 96);
                     loadrow<4>(w0 + 32, eU0 + (size_t)r * HID); }
  else             loadrow<12>(w0, eU0 + (size_t)r * HID + 16);
  if (q < 2) loadrow<8>(w1, eW1 + (size_t)r * HID + 32 * q);
  else       loadrow<8>(w1, eU1 + (size_t)r * HID + 32 * (q - 2));
  float bs0 = ebi0[r] + ebh0[r];
  float bs1 = ebi1[r] + ebh1[r];

  const float* xb = x + (size_t)b * (T_SEQ * DIN);

  if (tid >= 136 && tid < BUFSZ) { Abuf[tid] = 0.f; Bbuf[tid] = 0.f; }   // h-slots = 0 (both bufs)
  if (tid < 32) {
    float4 v = ((const float4*)xb)[tid];
    ((float4*)Abuf)[tid + tid / 12] = v;                       // x_0 (padded)
  }
  float c0 = 0.f, c1 = 0.f;
  __syncthreads();

  // ---------------- phase 1: layer-skewed fused encoder (ONE barrier per step) ----------------
  // Phase t computes h0(t)   from [x(t)      | h0(t-1)]  (op0 region of R)
  //            and   h1(t-1) from [h0(t-1)   | h1(t-2)]  (op1 region of R)
  auto enc_phase = [&](float* R, float* W, int t) {
    float4 xn;
    const bool pf = (tid < 32) && (t + 1 < T_SEQ);
    if (pf) xn = ((const float4*)(xb + (size_t)(t + 1) * DIN))[tid];

    float p0 = dotp<12>(w0, (const float4*)R + 13 * q);
    float p1 = dotp<8>(w1, (const float4*)R + 52 + 9 * q);
    p0 = dpp_add<0xB1>(p0);
    p1 = dpp_add<0xB1>(p1);
    p0 = dpp_add<0x4E>(p0);
    p1 = dpp_add<0x4E>(p1);
    p0 += bs0;
    p1 += bs1;
    float h0v = cell_update(p0, gsc, gscl, gof, c0);
    float c1n = c1;
    float h1v = cell_update(p1, gsc, gscl, gof, c1n);
    if ((tid & 15) < 2)
      W[(tid & 15) ? (EOP1 + j + 4 * (j >> 5)) : ((j < 16) ? 136 + j : 140 + j)] = h0v;
    if (t > 0) {                               // t=0: h1(-1)/c1 stay at zero init
      c1 = c1n;
      if ((tid & 15) == 0) W[280 + j + 4 * (j >> 5)] = h1v;
    }
    if (pf) ((float4*)W)[tid + tid / 12] = xn; // stage x_{t+1}
    bar_lds();
  };

#pragma unroll 1
  for (int t = 0; t < T_SEQ; t += 2) {
    enc_phase(Abuf, Bbuf, t);
    enc_phase(Bbuf, Abuf, t + 1);
  }
  // epilogue phase: h1(T-1) from [h0(T-1) | h1(T-2)], final state lives in Abuf
  {
    float p1 = dotp<8>(w1, (const float4*)Abuf + 52 + 9 * q);
    p1 = dpp_add<0xB1>(p1);
    p1 = dpp_add<0x4E>(p1);
    p1 += bs1;
    float h1v = cell_update(p1, gsc, gscl, gof, c1);
    bar_lds();                                 // all reads of old h1 slot done before overwrite
    if ((tid & 15) == 0) Abuf[280 + j + 4 * (j >> 5)] = h1v;
  }
  float* R = Abuf;
  float* W = Bbuf;
  __syncthreads();

  // ---------------- transition: decoder weights + re-layout states ----------------
  const float* C0   = ws;
  const float* fcbt_arr = ws + 256 * HID;
  if (q < 2) loadrow<8>(w0, C0  + (size_t)r * HID + 32 * q);
  else       loadrow<8>(w0, dU0 + (size_t)r * HID + 32 * (q - 2));
  if (q < 2) loadrow<8>(w1, dW1 + (size_t)r * HID + 32 * q);
  else       loadrow<8>(w1, dU1 + (size_t)r * HID + 32 * (q - 2));
  float bs0d = dbi0[r] + dbh0[r];
  float bs1d = dbi1[r] + dbh1[r];
  float fcbt = fcbt_arr[r];

  const int e  = tid & 7;      // fc k-slice (8 floats)
  const int oo = tid >> 3;     // fc output index [0,128)
  float fw[8];
  loadrow<2>(fw, fcW + (size_t)oo * HID + 8 * e);
  float fb = fcb[oo];

  c0 = tanh_full(c0);
  c1 = tanh_full(c1);
  float hv = 0.f;
  if (tid < 64)        hv = tanh_full(R[(tid < 16) ? 136 + tid : 140 + tid]);        // h0enc
  else if (tid < 128)  { int jj = tid - 64; hv = tanh_full(R[280 + jj + 4*(jj>>5)]); } // h1enc
  __syncthreads();
  if (tid < 64)        R[72 + tid + 4 * (tid >> 5)] = hv;        // op0 h0 slot
  else if (tid < 128)  { int jj = tid - 64; R[216 + jj + 4*(jj>>5)] = hv; } // op1 h1old
  else if (tid < 196)  R[tid - 128] = 0.f;                       // op0 h1 slot = 0 (t=0: pred_{-1}=0)
  __syncthreads();

  float* outb = out + (size_t)b * (T_SEQ * DOUT);

  // ---------------- phase 2: autoregressive decoder (fc folded via C0) ----------------
  auto dec_step = [&](float* R_, float* W_, int t) {
    // layer-0 dot on [h1_{t-1} | h0_{t-1}]  (K=128)
    float p0 = dotp<8>(w0, (const float4*)R_ + 9 * q);
    // fc for pred_{t-1} (output only; off the critical path), reads R_ h1 slot
    float s = dotp<2>(fw, (const float4*)R_ + 2 * e + (e >> 2));
    p0 = dpp_add<0xB1>(p0);
    p0 = dpp_add<0x4E>(p0);
    p0 += bs0d;
    if (t > 0) p0 += fcbt;                      // composite fcb term (absent at t=0)
    float h0v = cell_update(p0, gsc, gscl, gof, c0);
    if ((tid & 15) < 2)
      W_[(tid & 15) ? (72 + j + 4 * (j >> 5)) : (DOP1 + j + 4 * (j >> 5))] = h0v;
    s = dpp_add<0xB1>(s);
    s = dpp_add<0x4E>(s);
    s += dpp_mov<0x104>(s);                     // e-group upper-half add (valid at e==0 lanes)
    if (e == 0 && t > 0) outb[(size_t)(t - 1) * DOUT + oo] = s + fb;
    bar_lds();

    const float* bb = (q < 2) ? W_ : R_;        // [h0new | h1old]
    float p1 = dotp<8>(w1, (const float4*)bb + 36 + 9 * q);
    p1 = dpp_add<0xB1>(p1);
    p1 = dpp_add<0x4E>(p1);
    p1 += bs1d;
    float h1v = cell_update(p1, gsc, gscl, gof, c1);
    if ((tid & 15) < 2)
      W_[(tid & 15) ? (j + 4 * (j >> 5)) : (216 + j + 4 * (j >> 5))] = h1v;
    bar_lds();
  };

#pragma unroll 1
  for (int t = 0; t < T_SEQ; t += 2) {
    dec_step(R, W, t);
    dec_step(W, R, t + 1);
  }

  // epilogue: pred_{1023} from final h1 (in R)
  float s = dotp<2>(fw, (const float4*)R + 2 * e + (e >> 2));
  s = dpp_add<0xB1>(s);
  s = dpp_add<0x4E>(s);
  s += dpp_mov<0x104>(s);
  if (e == 0) outb[(size_t)(T_SEQ - 1) * DOUT + oo] = s + fb;
}

extern "C" void kernel_launch(void* const* d_in, const int* in_sizes, int n_in,
                              void* d_out, int out_size, void* d_ws, size_t ws_size,
                              hipStream_t stream) {
  (void)in_sizes; (void)n_in; (void)ws_size; (void)out_size;
  const float* x    = (const float*)d_in[0];
  const float* eW0  = (const float*)d_in[1];
  const float* eU0  = (const float*)d_in[2];
  const float* ebi0 = (const float*)d_in[3];
  const float* ebh0 = (const float*)d_in[4];
  const float* eW1  = (const float*)d_in[5];
  const float* eU1  = (const float*)d_in[6];
  const float* ebi1 = (const float*)d_in[7];
  const float* ebh1 = (const float*)d_in[8];
  const float* dW0  = (const float*)d_in[9];
  const float* dU0  = (const float*)d_in[10];
  const float* dbi0 = (const float*)d_in[11];
  const float* dbh0 = (const float*)d_in[12];
  const float* dW1  = (const float*)d_in[13];
  const float* dU1  = (const float*)d_in[14];
  const float* dbi1 = (const float*)d_in[15];
  const float* dbh1 = (const float*)d_in[16];
  const float* fcW  = (const float*)d_in[17];
  const float* fcb  = (const float*)d_in[18];
  float* ws  = (float*)d_ws;
  float* out = (float*)d_out;

  hipLaunchKernelGGL(prep_kernel, dim3(256), dim3(64), 0, stream, dW0, fcW, fcb, ws);
  hipLaunchKernelGGL(lstm_ae_kernel, dim3(NBATCH), dim3(1024), 0, stream,
                     x, eW0, eU0, ebi0, ebh0, eW1, eU1, ebi1, ebh1,
                     dW0, dU0, dbi0, dbh0, dW1, dU1, dbi1, dbh1,
                     fcW, fcb, ws, out);
}

// Round 4
// 2147.320 us; speedup vs baseline: 1.1298x; 1.1008x over previous
//
#include <hip/hip_runtime.h>

#define T_SEQ 1024
#define NBATCH 256
#define DIN 128
#define HID 64
#define DOUT 128

// ---------------- LDS layouts (512-thread version, 2-slice K-split) ----------------
// Encoder (per ping-pong buffer of 340 floats):
//  op0 [0..200):  [x:128 | h0:64] = 192 floats, 2 k-slices of 96, slice stride 100:
//                 x[k] -> (k<96) ? k : 100+(k-96);  h0[j] -> 132+j
//  op1 [200..336): [h0:64 | h1:64], 2 slices of 64, stride 68:
//                 h0[j] -> 200+j;  h1[j] -> 268+j
// Decoder (overlaid):
//  op0 [0..136):   [h1:64 | h0:64], stride 68: h1[i] -> i, h0[i] -> 68+i
//  op1 [136..272): [h0new:64 | h1old:64]: h0new[i] -> 136+i, h1old[i] -> 204+i
#define EOP1 200
#define SL1 68
#define DOP1 136
#define BUFSZ 340

#define TWO_LOG2E 2.8853900817779268f   // 2*log2(e)

typedef float v2f __attribute__((ext_vector_type(2)));

__device__ __forceinline__ float rcp_f(float x) { return __builtin_amdgcn_rcpf(x); }

__device__ __forceinline__ float exp2_f(float x) {
#if __has_builtin(__builtin_amdgcn_exp2f)
  return __builtin_amdgcn_exp2f(x);
#else
  return exp2f(x);
#endif
}

// tanh(x) with pre-scaled argument y = x*TWO_LOG2E:  tanh = 1 - 2/(1+2^y); inf-safe
__device__ __forceinline__ float tanh_pre(float y) {
  float m = exp2_f(y);
  return fmaf(-2.0f, rcp_f(1.0f + m), 1.0f);
}
__device__ __forceinline__ float tanh_full(float x) { return tanh_pre(x * TWO_LOG2E); }

// quad-perm DPP butterfly add (lane^1: 0xB1, lane^2: 0x4E) on the VALU pipe
template<int CTRL>
__device__ __forceinline__ float dpp_add(float v) {
  int p = __builtin_amdgcn_update_dpp(0, __float_as_int(v), CTRL, 0xF, 0xF, true);
  return v + __int_as_float(p);
}

// DPP mov: CTRL 0x100|N = row_shl:N -> dst lane i gets src lane i+N (within 16-lane row)
template<int CTRL>
__device__ __forceinline__ float dpp_mov(float v) {
  int p = __builtin_amdgcn_update_dpp(0, __float_as_int(v), CTRL, 0xF, 0xF, true);
  return __int_as_float(p);
}

// LDS-only barrier: do NOT drain vmcnt (x prefetch loads / out stores stay in flight).
__device__ __forceinline__ void bar_lds() {
  asm volatile("s_waitcnt lgkmcnt(0)\n\ts_barrier" ::: "memory");
}

template<int N4>
__device__ __forceinline__ void loadrow(float* w, const float* p) {
#pragma unroll
  for (int k = 0; k < N4; ++k) {
    float4 q = ((const float4*)p)[k];
    w[4*k+0] = q.x; w[4*k+1] = q.y; w[4*k+2] = q.z; w[4*k+3] = q.w;
  }
}

// Packed-fp32 dot: K4 float4 iterations = 2*K4 v_pk_fma_f32 (4 independent fp32 chains).
template<int K4>
__device__ __forceinline__ float dotp(const float* wf, const float4* v) {
  const v2f* w = (const v2f*)wf;
  v2f a0 = {0.f, 0.f}, a1 = {0.f, 0.f};
#pragma unroll
  for (int k = 0; k < K4; ++k) {
    float4 q = v[k];
    v2f q0 = {q.x, q.y};
    v2f q1 = {q.z, q.w};
    a0 = __builtin_elementwise_fma(w[2*k+0], q0, a0);
    a1 = __builtin_elementwise_fma(w[2*k+1], q1, a1);
  }
  v2f s = a0 + a1;   // v_pk_add_f32
  return s.x + s.y;
}

// Lane map (512 thr): q = tid&1 (k-half), g = (tid>>1)&3 (gate i,f,g,o), j = tid>>3 (unit).
// After the q-butterfly (xor1), each 8-lane group holds: lanes 0,1 = i; 2,3 = f;
// 4,5 = g~; 6,7 = o (all full dots). Gather f/g~/o into lanes 0,1 with row_shl:2/4/6.
// c/h are VALID ONLY in lanes 0,1 of each 8-group — exactly the writer lanes.
__device__ __forceinline__ float cell_update(float pre, float gsc, float gscl, float gof, float& c) {
  float a  = fmaf(gsc, tanh_pre(pre * gscl), gof);  // sigmoid for i,f,o ; tanh for g
  float f_s = dpp_mov<0x102>(a);   // lane i <- i+2   (f)
  float g_t = dpp_mov<0x104>(a);   // lane i <- i+4   (g~)
  float o_s = dpp_mov<0x106>(a);   // lane i <- i+6   (o)
  c = fmaf(f_s, c, a * g_t);       // a == i in lanes 0,1
  return o_s * tanh_full(c);
}

// ---------------- prep kernel: C0 = dWih0 @ fcW  [256x64], fcbt = dWih0 @ fcb ----------------
__global__ void prep_kernel(const float* __restrict__ dWih0,
                            const float* __restrict__ fcW,
                            const float* __restrict__ fcb,
                            float* __restrict__ ws) {
  const int r = (int)blockIdx.x;           // 256 blocks
  const int jj = (int)threadIdx.x;         // 64 threads
  const float* wr = dWih0 + (size_t)r * DIN;
  float acc = 0.f;
  for (int o = 0; o < DIN; ++o) acc = fmaf(wr[o], fcW[(size_t)o * HID + jj], acc);
  ws[(size_t)r * HID + jj] = acc;
  if (jj == 0) {
    float a = 0.f;
    for (int o = 0; o < DIN; ++o) a = fmaf(wr[o], fcb[o], a);
    ws[256 * HID + r] = a;
  }
}

// ---------------- main persistent kernel: 1 block / batch element, 512 threads ----------------
__global__ __launch_bounds__(512, 2) void lstm_ae_kernel(
    const float* __restrict__ x,
    const float* __restrict__ eW0, const float* __restrict__ eU0,
    const float* __restrict__ ebi0, const float* __restrict__ ebh0,
    const float* __restrict__ eW1, const float* __restrict__ eU1,
    const float* __restrict__ ebi1, const float* __restrict__ ebh1,
    const float* __restrict__ dW0, const float* __restrict__ dU0,
    const float* __restrict__ dbi0, const float* __restrict__ dbh0,
    const float* __restrict__ dW1, const float* __restrict__ dU1,
    const float* __restrict__ dbi1, const float* __restrict__ dbh1,
    const float* __restrict__ fcW, const float* __restrict__ fcb,
    const float* __restrict__ ws,
    float* __restrict__ out)
{
  __shared__ __align__(16) float Abuf[BUFSZ];
  __shared__ __align__(16) float Bbuf[BUFSZ];

  const int tid = (int)threadIdx.x;
  const int b   = (int)blockIdx.x;
  const int q   = tid & 1;
  const int g   = (tid >> 1) & 3;
  const int j   = tid >> 3;
  const int r   = g * HID + j;
  const int l8  = tid & 7;

  const float gsc  = (g == 2) ? 1.0f : 0.5f;
  const float gof  = (g == 2) ? 0.0f : 0.5f;
  const float gscl = gsc * TWO_LOG2E;

  float w0[96];
  float w1[64];

  // ---------------- encoder weights ----------------
  // L0 K=192 = [x(128) | h0(64)], half q covers 96: q0 = eW0[0..96); q1 = eW0[96..128)+eU0[0..64)
  if (q == 0) loadrow<24>(w0, eW0 + (size_t)r * DIN);
  else { loadrow<8>(w0, eW0 + (size_t)r * DIN + 96);
         loadrow<16>(w0 + 32, eU0 + (size_t)r * HID); }
  // L1 K=128 = [h0 | h1]: q0 = eW1 row, q1 = eU1 row
  if (q == 0) loadrow<16>(w1, eW1 + (size_t)r * HID);
  else        loadrow<16>(w1, eU1 + (size_t)r * HID);
  float bs0 = ebi0[r] + ebh0[r];
  float bs1 = ebi1[r] + ebh1[r];

  const float* xb = x + (size_t)b * (T_SEQ * DIN);

  if (tid >= 132 && tid < BUFSZ) Abuf[tid] = 0.f;   // h0 slot + op1 of A
  if (tid >= 200 && tid < BUFSZ) Bbuf[tid] = 0.f;   // op1 of B (h1(-1) = 0)
  if (tid < 32) {
    float4 v = ((const float4*)xb)[tid];
    ((float4*)Abuf)[tid + tid / 24] = v;            // x_0: f4 slot i + (i>=24)
  }
  float c0 = 0.f, c1 = 0.f;
  __syncthreads();

  // ---------------- phase 1: layer-skewed fused encoder (ONE barrier per phase) ----------------
  // Phase t computes h0(t)   from [x(t)    | h0(t-1)]  (op0 of R)
  //            and   h1(t-1) from [h0(t-1) | h1(t-2)]  (op1 of R)
  auto enc_phase = [&](float* R, float* W, int t) {
    float4 xn;
    const bool pf = (tid < 32) && (t + 1 < T_SEQ);
    if (pf) xn = ((const float4*)(xb + (size_t)(t + 1) * DIN))[tid];

    float p0 = dotp<24>(w0, (const float4*)R + 25 * q);
    float p1 = dotp<16>(w1, (const float4*)R + 50 + 17 * q);
    p0 = dpp_add<0xB1>(p0);
    p1 = dpp_add<0xB1>(p1);
    p0 += bs0;
    p1 += bs1;
    float h0v = cell_update(p0, gsc, gscl, gof, c0);
    float c1n = c1;
    float h1v = cell_update(p1, gsc, gscl, gof, c1n);
    if (l8 == 0)      W[EOP1 + j] = h0v;            // op1 slice0 (L1 input next phase)
    else if (l8 == 1) W[132 + j]  = h0v;            // op0 slice1 (L0 recurrent next phase)
    if (t > 0) {                                    // t=0: h1(-1)/c1 stay at zero init
      c1 = c1n;
      if (l8 == 0) W[EOP1 + SL1 + j] = h1v;         // op1 slice1
    }
    if (pf) ((float4*)W)[tid + tid / 24] = xn;      // stage x_{t+1}
    bar_lds();
  };

#pragma unroll 1
  for (int t = 0; t < T_SEQ; t += 2) {
    enc_phase(Abuf, Bbuf, t);
    enc_phase(Bbuf, Abuf, t + 1);
  }
  // epilogue phase: h1(T-1) from [h0(T-1) | h1(T-2)] in Abuf
  {
    float p1 = dotp<16>(w1, (const float4*)Abuf + 50 + 17 * q);
    p1 = dpp_add<0xB1>(p1);
    p1 += bs1;
    float h1v = cell_update(p1, gsc, gscl, gof, c1);
    bar_lds();                                      // reads of old h1 slot done before overwrite
    if (l8 == 0) Abuf[EOP1 + SL1 + j] = h1v;
  }
  float* R = Abuf;
  float* W = Bbuf;
  __syncthreads();

  // ---------------- transition: decoder weights + re-layout states ----------------
  const float* C0   = ws;
  const float* fcbt_arr = ws + 256 * HID;
  // dec L0 K=128 = [h1 | h0] (composite C0 handles pred->x fold): q0 = C0 row, q1 = dU0 row
  if (q == 0) loadrow<16>(w0, C0  + (size_t)r * HID);
  else        loadrow<16>(w0, dU0 + (size_t)r * HID);
  if (q == 0) loadrow<16>(w1, dW1 + (size_t)r * HID);
  else        loadrow<16>(w1, dU1 + (size_t)r * HID);
  float bs0d = dbi0[r] + dbh0[r];
  float bs1d = dbi1[r] + dbh1[r];
  float fcbt = fcbt_arr[r];

  const int e  = tid & 3;      // fc k-slice (16 floats)
  const int oo = tid >> 2;     // fc output index [0,128)
  float fw[16];
  loadrow<4>(fw, fcW + (size_t)oo * HID + 16 * e);
  float fb = fcb[oo];

  c0 = tanh_full(c0);
  c1 = tanh_full(c1);
  float hv = 0.f;
  if (tid < 64)        hv = tanh_full(R[132 + tid]);              // h0enc
  else if (tid < 128)  hv = tanh_full(R[EOP1 + SL1 + (tid - 64)]); // h1enc
  __syncthreads();
  if (tid < 64)        R[68 + tid] = hv;                  // dec op0 slice1 (h0)
  else if (tid < 128)  R[DOP1 + SL1 + (tid - 64)] = hv;   // dec op1 slice1 (h1old)
  else if (tid < 192)  R[tid - 128] = 0.f;                // dec op0 slice0 (h1) = 0 at t=0
  __syncthreads();

  float* outb = out + (size_t)b * (T_SEQ * DOUT);

  // ---------------- phase 2: autoregressive decoder (fc folded via C0) ----------------
  auto dec_step = [&](float* R_, float* W_, int t) {
    // layer-0 dot on [h1_{t-1} | h0_{t-1}]  (K=128)
    float p0 = dotp<16>(w0, (const float4*)R_ + 17 * q);
    // fc for pred_{t-1} (output only; off the critical path), reads R_ h1 slot (floats 0..63)
    float s = dotp<4>(fw, (const float4*)R_ + 4 * e);
    p0 = dpp_add<0xB1>(p0);
    p0 += bs0d;
    if (t > 0) p0 += fcbt;                          // composite fcb term (absent at t=0)
    float h0v = cell_update(p0, gsc, gscl, gof, c0);
    if (l8 == 0)      W_[DOP1 + j] = h0v;           // op1 slice0 (L1 input this step)
    else if (l8 == 1) W_[68 + j]   = h0v;           // op0 slice1 (L0 recurrent next step)
    s = dpp_add<0xB1>(s);
    s = dpp_add<0x4E>(s);
    if (e == 0 && t > 0) outb[(size_t)(t - 1) * DOUT + oo] = s + fb;
    bar_lds();

    const float* bb = (q == 0) ? W_ : R_;           // [h0new (W_) | h1old (R_)]
    float p1 = dotp<16>(w1, (const float4*)bb + 34 + 17 * q);
    p1 = dpp_add<0xB1>(p1);
    p1 += bs1d;
    float h1v = cell_update(p1, gsc, gscl, gof, c1);
    if (l8 == 0)      W_[j] = h1v;                  // op0 slice0 (fc + L0 next step)
    else if (l8 == 1) W_[DOP1 + SL1 + j] = h1v;     // op1 slice1 (L1 h1old next step)
    bar_lds();
  };

#pragma unroll 1
  for (int t = 0; t < T_SEQ; t += 2) {
    dec_step(R, W, t);
    dec_step(W, R, t + 1);
  }

  // epilogue: pred_{1023} from final h1 (in R floats 0..63)
  float s = dotp<4>(fw, (const float4*)R + 4 * e);
  s = dpp_add<0xB1>(s);
  s = dpp_add<0x4E>(s);
  if (e == 0) outb[(size_t)(T_SEQ - 1) * DOUT + oo] = s + fb;
}

extern "C" void kernel_launch(void* const* d_in, const int* in_sizes, int n_in,
                              void* d_out, int out_size, void* d_ws, size_t ws_size,
                              hipStream_t stream) {
  (void)in_sizes; (void)n_in; (void)ws_size; (void)out_size;
  const float* x    = (const float*)d_in[0];
  const float* eW0  = (const float*)d_in[1];
  const float* eU0  = (const float*)d_in[2];
  const float* ebi0 = (const float*)d_in[3];
  const float* ebh0 = (const float*)d_in[4];
  const float* eW1  = (const float*)d_in[5];
  const float* eU1  = (const float*)d_in[6];
  const float* ebi1 = (const float*)d_in[7];
  const float* ebh1 = (const float*)d_in[8];
  const float* dW0  = (const float*)d_in[9];
  const float* dU0  = (const float*)d_in[10];
  const float* dbi0 = (const float*)d_in[11];
  const float* dbh0 = (const float*)d_in[12];
  const float* dW1  = (const float*)d_in[13];
  const float* dU1  = (const float*)d_in[14];
  const float* dbi1 = (const float*)d_in[15];
  const float* dbh1 = (const float*)d_in[16];
  const float* fcW  = (const float*)d_in[17];
  const float* fcb  = (const float*)d_in[18];
  float* ws  = (float*)d_ws;
  float* out = (float*)d_out;

  hipLaunchKernelGGL(prep_kernel, dim3(256), dim3(64), 0, stream, dW0, fcW, fcb, ws);
  hipLaunchKernelGGL(lstm_ae_kernel, dim3(NBATCH), dim3(512), 0, stream,
                     x, eW0, eU0, ebi0, ebh0, eW1, eU1, ebi1, ebh1,
                     dW0, dU0, dbi0, dbh0, dW1, dU1, dbi1, dbh1,
                     fcW, fcb, ws, out);
}